// Round 4
// baseline (264.831 us; speedup 1.0000x reference)
//
#include <hip/hip_runtime.h>
#include <math.h>

#define N_ELEMS 200000
#define D 512
#define NCLS 2
#define NINS 8
#define NTHR 1024          // 16 waves, one block, one CU
#define NWAVE 16

typedef unsigned long long u64;
typedef unsigned int u32;

// Order-preserving float->uint map: a > b  <=>  mono(a) > mono(b)
__device__ __forceinline__ u32 mono(float f) {
    u32 u = __float_as_uint(f);
    return u ^ (u32)(((int)u >> 31) | 0x80000000);
}

// key packs (value, index): larger value wins; equal value -> SMALLER index wins
// (jax top_k tie-break) because low 32 bits hold ~i. 0 is a safe "empty" sentinel
// (would require v = negative-NaN to collide; inputs are randn).
__device__ __forceinline__ u64 make_key(float v, int i) {
    return ((u64)mono(v) << 32) | (u32)(~(u32)i);
}
__device__ __forceinline__ int key_idx(u64 k) { return (int)(~(u32)k); }

__device__ __forceinline__ u64 shfl_xor_u64(u64 x, int m) {
    u32 lo = (u32)x, hi = (u32)(x >> 32);
    lo = __shfl_xor(lo, m, 64);
    hi = __shfl_xor(hi, m, 64);
    return ((u64)hi << 32) | lo;
}

__device__ __forceinline__ u64 wave_max_u64(u64 k) {
#pragma unroll
    for (int m = 1; m < 64; m <<= 1) {
        u64 o = shfl_xor_u64(k, m);
        if (o > k) k = o;
    }
    return k;
}

// Insert into sorted-descending 8-list (registers, static indexing, early exit).
__device__ __forceinline__ void ins8(u64 (&L)[8], u64 k) {
    if (k <= L[7]) return;
    L[7] = k;
#pragma unroll
    for (int j = 7; j > 0; --j) {
        if (L[j] > L[j - 1]) { u64 t = L[j - 1]; L[j - 1] = L[j]; L[j] = t; }
    }
}

__global__ __launch_bounds__(NTHR) void ins_once(const int* __restrict__ bl_ptr,
                                                 const float* __restrict__ A,
                                                 const float* __restrict__ h,
                                                 const float* __restrict__ W,
                                                 const float* __restrict__ bvec,
                                                 float* __restrict__ out) {
    const int tid  = threadIdx.x;
    const int wid  = tid >> 6;     // 0..15
    const int lane = tid & 63;
    const int bl   = bl_ptr[0];

    __shared__ u64 cand[2][NWAVE][NINS];   // per-wave top-8s, both lists (2 KB)
    __shared__ int fidx[2 * NINS];

    // ---- Phase 1: per-thread sorted top-8 / bottom-8 over strided elements ----
    const float2* A2 = (const float2*)A;   // A is (N,1,2) contiguous

    u64 tl[8], blst[8];
#pragma unroll
    for (int j = 0; j < 8; ++j) { tl[j] = 0ULL; blst[j] = 0ULL; }

    // 196 strided elements per thread, grouped 4 at a time for load ILP.
#pragma unroll 1
    for (int m = 0; m < 49; ++m) {
        int i0 = tid + m * 4096;
        int i1 = i0 + 1024, i2 = i0 + 2048, i3 = i0 + 3072;
        float2 a0, a1, a2, a3;
        bool v0 = i0 < N_ELEMS, v1 = i1 < N_ELEMS, v2 = i2 < N_ELEMS, v3 = i3 < N_ELEMS;
        if (v0) a0 = A2[i0];
        if (v1) a1 = A2[i1];
        if (v2) a2 = A2[i2];
        if (v3) a3 = A2[i3];
        if (v0) { float v = bl ? a0.y : a0.x; ins8(tl, make_key(v, i0)); ins8(blst, make_key(-v, i0)); }
        if (v1) { float v = bl ? a1.y : a1.x; ins8(tl, make_key(v, i1)); ins8(blst, make_key(-v, i1)); }
        if (v2) { float v = bl ? a2.y : a2.x; ins8(tl, make_key(v, i2)); ins8(blst, make_key(-v, i2)); }
        if (v3) { float v = bl ? a3.y : a3.x; ins8(tl, make_key(v, i3)); ins8(blst, make_key(-v, i3)); }
    }

    // ---- per-wave merge: 8 rounds of wave-max over each thread's list head ----
    {
        u64 mine = 0;
#pragma unroll
        for (int r = 0; r < NINS; ++r) {
            u64 w = wave_max_u64(tl[0]);
            if (lane == r) mine = w;
            if (tl[0] == w) {   // unique keys: only the head can match
                tl[0] = tl[1]; tl[1] = tl[2]; tl[2] = tl[3]; tl[3] = tl[4];
                tl[4] = tl[5]; tl[5] = tl[6]; tl[6] = tl[7]; tl[7] = 0ULL;
            }
        }
        if (lane < 8) cand[0][wid][lane] = mine;
    }
    {
        u64 mine = 0;
#pragma unroll
        for (int r = 0; r < NINS; ++r) {
            u64 w = wave_max_u64(blst[0]);
            if (lane == r) mine = w;
            if (blst[0] == w) {
                blst[0] = blst[1]; blst[1] = blst[2]; blst[2] = blst[3]; blst[3] = blst[4];
                blst[4] = blst[5]; blst[5] = blst[6]; blst[6] = blst[7]; blst[7] = 0ULL;
            }
        }
        if (lane < 8) cand[1][wid][lane] = mine;
    }
    __syncthreads();

    // ---- Phase 2: wave 0 merges 16x8 top keys, wave 1 bottom, in parallel ----
    if (wid < 2) {
        u64 ka = cand[wid][lane >> 2][lane & 3];
        u64 kb = cand[wid][lane >> 2][4 + (lane & 3)];
        int got = 0;
#pragma unroll
        for (int r = 0; r < NINS; ++r) {
            u64 m_ = ka > kb ? ka : kb;
            u64 w = wave_max_u64(m_);
            if (lane == r) got = key_idx(w);
            if (ka == w) ka = 0ULL;
            if (kb == w) kb = 0ULL;
        }
        if (lane < 8) fidx[wid * NINS + lane] = got;
    }
    __syncthreads();

    // ---- Phase 3: one wave per selected row; two 512-length dot products ----
    const long long row = fidx[wid];
    const float4* h4 = (const float4*)(h + row * (long long)D);
    const float2* W2 = (const float2*)W;

    float s0 = 0.f, s1 = 0.f;
#pragma unroll
    for (int it = 0; it < 2; ++it) {
        int d4 = lane + it * 64;           // float4 index, coalesced per wave
        float4 x = h4[d4];
        float2 w0 = W2[d4 * 4 + 0];
        float2 w1 = W2[d4 * 4 + 1];
        float2 w2 = W2[d4 * 4 + 2];
        float2 w3 = W2[d4 * 4 + 3];
        s0 += x.x * w0.x + x.y * w1.x + x.z * w2.x + x.w * w3.x;
        s1 += x.x * w0.y + x.y * w1.y + x.z * w2.y + x.w * w3.y;
    }
#pragma unroll
    for (int m = 1; m < 64; m <<= 1) {
        s0 += __shfl_xor(s0, m, 64);
        s1 += __shfl_xor(s1, m, 64);
    }
    if (lane == 0) {
        float l0 = s0 + bvec[0];
        float l1 = s1 + bvec[1];
        float mx = fmaxf(l0, l1);
        float e0 = expf(l0 - mx), e1 = expf(l1 - mx);
        float inv = 1.0f / (e0 + e1);
        out[16 + wid * 2 + 0] = l0;        // logits_unnorm
        out[16 + wid * 2 + 1] = l1;
        out[48 + wid * 2 + 0] = e0 * inv;  // softmax
        out[48 + wid * 2 + 1] = e1 * inv;
    }
    if (tid < 16) out[tid] = (tid < 8) ? 1.0f : 0.0f;  // ins_labels
}

extern "C" void kernel_launch(void* const* d_in, const int* in_sizes, int n_in,
                              void* d_out, int out_size, void* d_ws, size_t ws_size,
                              hipStream_t stream) {
    const int*   bl = (const int*)  d_in[0];
    const float* h  = (const float*)d_in[1];
    const float* A  = (const float*)d_in[2];
    const float* W  = (const float*)d_in[3];
    const float* b  = (const float*)d_in[4];
    float* out = (float*)d_out;

    // Single graph node: no workspace, no atomics, no fences, no memset.
    ins_once<<<1, NTHR, 0, stream>>>(bl, A, h, W, b, out);
}

// Round 5
// 25.272 us; speedup vs baseline: 10.4794x; 10.4794x over previous
//
#include <hip/hip_runtime.h>
#include <math.h>

#define N_ELEMS 200000
#define D 512
#define NCLS 2
#define NINS 8
#define NBLK1 128
#define NTHR1 512          // 8 waves
#define NTHR2 1024         // 16 waves

typedef unsigned long long u64;
typedef unsigned int u32;

// Order-preserving float->uint map: a > b  <=>  mono(a) > mono(b)
__device__ __forceinline__ u32 mono(float f) {
    u32 u = __float_as_uint(f);
    return u ^ (u32)(((int)u >> 31) | 0x80000000);
}

// key packs (value, index): larger value wins; equal value -> SMALLER index wins
// (jax top_k tie-break) because low 32 bits hold ~i. 0 is a safe empty sentinel.
__device__ __forceinline__ u64 make_key(float v, int i) {
    return ((u64)mono(v) << 32) | (u32)(~(u32)i);
}
__device__ __forceinline__ int key_idx(u64 k) { return (int)(~(u32)k); }

__device__ __forceinline__ u64 shfl_xor_u64(u64 x, int m) {
    u32 lo = (u32)x, hi = (u32)(x >> 32);
    lo = __shfl_xor(lo, m, 64);
    hi = __shfl_xor(hi, m, 64);
    return ((u64)hi << 32) | lo;
}

__device__ __forceinline__ u64 wave_max_u64(u64 k) {
#pragma unroll
    for (int m = 1; m < 64; m <<= 1) {
        u64 o = shfl_xor_u64(k, m);
        if (o > k) k = o;
    }
    return k;
}

// ---------------- Kernel 1: per-block top-8 / bottom-8 of A_I ----------------
__global__ __launch_bounds__(NTHR1) void scan_partial(const int* __restrict__ bl_ptr,
                                                      const float* __restrict__ A,
                                                      u64* __restrict__ wsTop,
                                                      u64* __restrict__ wsBot) {
    const int tid  = threadIdx.x;
    const int blk  = blockIdx.x;
    const int wid  = tid >> 6;     // 0..7
    const int lane = tid & 63;
    const int bl   = bl_ptr[0];

    __shared__ u64 cand[2][8][NINS];   // per-wave top-8s (1 KB)

    const int chunk = (N_ELEMS + NBLK1 - 1) / NBLK1;   // 1563
    const int start = blk * chunk;
    const int end   = min(N_ELEMS, start + chunk);
    const float2* A2 = (const float2*)A;               // A is (N,1,2) -> float2/row

    u64 t0, t1, t2, t3, b0, b1, b2, b3;
    {
        int i0 = start + tid, i1 = i0 + NTHR1, i2 = i1 + NTHR1, i3 = i2 + NTHR1;
        float2 a;
        if (i0 < end) { a = A2[i0]; float v = bl ? a.y : a.x; t0 = make_key(v, i0); b0 = make_key(-v, i0); } else { t0 = b0 = 0; }
        if (i1 < end) { a = A2[i1]; float v = bl ? a.y : a.x; t1 = make_key(v, i1); b1 = make_key(-v, i1); } else { t1 = b1 = 0; }
        if (i2 < end) { a = A2[i2]; float v = bl ? a.y : a.x; t2 = make_key(v, i2); b2 = make_key(-v, i2); } else { t2 = b2 = 0; }
        if (i3 < end) { a = A2[i3]; float v = bl ? a.y : a.x; t3 = make_key(v, i3); b3 = make_key(-v, i3); } else { t3 = b3 = 0; }
    }

#pragma unroll
    for (int r = 0; r < NINS; ++r) {            // top list: shfl-only, no barriers
        u64 m01 = t0 > t1 ? t0 : t1;
        u64 m23 = t2 > t3 ? t2 : t3;
        u64 lm  = m01 > m23 ? m01 : m23;
        u64 w   = wave_max_u64(lm);
        if (lane == 0) cand[0][wid][r] = w;
        if (t0 == w) t0 = 0; if (t1 == w) t1 = 0; if (t2 == w) t2 = 0; if (t3 == w) t3 = 0;
    }
#pragma unroll
    for (int r = 0; r < NINS; ++r) {            // bottom list
        u64 m01 = b0 > b1 ? b0 : b1;
        u64 m23 = b2 > b3 ? b2 : b3;
        u64 lm  = m01 > m23 ? m01 : m23;
        u64 w   = wave_max_u64(lm);
        if (lane == 0) cand[1][wid][r] = w;
        if (b0 == w) b0 = 0; if (b1 == w) b1 = 0; if (b2 == w) b2 = 0; if (b3 == w) b3 = 0;
    }
    __syncthreads();

    // wave 0 merges top (8x8=64 keys, 1/lane), wave 1 merges bottom — in parallel
    if (wid < 2) {
        u64 k = cand[wid][lane >> 3][lane & 7];
        u64 mine = 0;
#pragma unroll
        for (int r = 0; r < NINS; ++r) {
            u64 w = wave_max_u64(k);
            if (lane == r) mine = w;
            if (k == w) k = 0;
        }
        u64* dst = (wid == 0) ? wsTop : wsBot;
        if (lane < NINS) dst[blk * NINS + lane] = mine;    // sorted descending
    }
}

// ------------- Kernel 2: global merge + gather + matmul + softmax -------------
__global__ __launch_bounds__(NTHR2) void finalize(const float* __restrict__ h,
                                                  const float* __restrict__ W,
                                                  const float* __restrict__ bvec,
                                                  const u64* __restrict__ wsTop,
                                                  const u64* __restrict__ wsBot,
                                                  float* __restrict__ out) {
    const int tid  = threadIdx.x;
    const int wid  = tid >> 6;     // 0..15
    const int lane = tid & 63;

    __shared__ u64 cand2[16][NINS];    // stage-1 per-wave results (2 KB)
    __shared__ int fidx[2 * NINS];

    // Stage 1: waves 0-7 reduce the 1024 top keys (128/wave, 2/lane),
    //          waves 8-15 reduce the 1024 bottom keys. All parallel.
    {
        const u64* src = (wid < 8) ? wsTop : wsBot;
        const int base = (wid & 7) * 128;
        u64 ka = src[base + lane];
        u64 kb = src[base + 64 + lane];
        u64 mine = 0;
#pragma unroll
        for (int r = 0; r < NINS; ++r) {
            u64 m_ = ka > kb ? ka : kb;
            u64 w  = wave_max_u64(m_);
            if (lane == r) mine = w;
            if (ka == w) ka = 0;
            if (kb == w) kb = 0;
        }
        if (lane < NINS) cand2[wid][lane] = mine;
    }
    __syncthreads();

    // Stage 2: wave 0 merges the 64 top candidates (1/lane), wave 8 the bottom.
    if ((wid & 7) == 0) {
        const u64* flat = &cand2[(wid >> 3) * 8][0];   // 64 contiguous keys
        u64 k = flat[lane];
        int got = 0;
#pragma unroll
        for (int r = 0; r < NINS; ++r) {
            u64 w = wave_max_u64(k);
            if (lane == r) got = key_idx(w);
            if (k == w) k = 0;
        }
        if (lane < NINS) fidx[(wid >> 3) * NINS + lane] = got;
    }
    __syncthreads();

    // Phase 3: one wave per selected row; two 512-length dot products.
    const long long row = fidx[wid];
    const float4* h4 = (const float4*)(h + row * (long long)D);
    const float2* W2 = (const float2*)W;

    float s0 = 0.f, s1 = 0.f;
#pragma unroll
    for (int it = 0; it < 2; ++it) {
        int d4 = lane + it * 64;           // float4 index, coalesced per wave
        float4 x = h4[d4];
        float2 w0 = W2[d4 * 4 + 0];
        float2 w1 = W2[d4 * 4 + 1];
        float2 w2 = W2[d4 * 4 + 2];
        float2 w3 = W2[d4 * 4 + 3];
        s0 += x.x * w0.x + x.y * w1.x + x.z * w2.x + x.w * w3.x;
        s1 += x.x * w0.y + x.y * w1.y + x.z * w2.y + x.w * w3.y;
    }
#pragma unroll
    for (int m = 1; m < 64; m <<= 1) {
        s0 += __shfl_xor(s0, m, 64);
        s1 += __shfl_xor(s1, m, 64);
    }
    if (lane == 0) {
        float l0 = s0 + bvec[0];
        float l1 = s1 + bvec[1];
        float mx = fmaxf(l0, l1);
        float e0 = expf(l0 - mx), e1 = expf(l1 - mx);
        float inv = 1.0f / (e0 + e1);
        out[16 + wid * 2 + 0] = l0;        // logits_unnorm
        out[16 + wid * 2 + 1] = l1;
        out[48 + wid * 2 + 0] = e0 * inv;  // softmax
        out[48 + wid * 2 + 1] = e1 * inv;
    }
    if (tid < 16) out[tid] = (tid < 8) ? 1.0f : 0.0f;  // ins_labels
}

extern "C" void kernel_launch(void* const* d_in, const int* in_sizes, int n_in,
                              void* d_out, int out_size, void* d_ws, size_t ws_size,
                              hipStream_t stream) {
    const int*   bl = (const int*)  d_in[0];
    const float* h  = (const float*)d_in[1];
    const float* A  = (const float*)d_in[2];
    const float* W  = (const float*)d_in[3];
    const float* b  = (const float*)d_in[4];
    float* out = (float*)d_out;

    // ws layout: wsTop u64[1024] @0 (8KB) | wsBot u64[1024] @8KB. No counters.
    char* ws = (char*)d_ws;
    u64* wsTop = (u64*)(ws + 0);
    u64* wsBot = (u64*)(ws + 8192);

    scan_partial<<<NBLK1, NTHR1, 0, stream>>>(bl, A, wsTop, wsBot);
    finalize<<<1, NTHR2, 0, stream>>>(h, W, b, wsTop, wsBot, out);
}